// Round 1
// baseline (331.104 us; speedup 1.0000x reference)
//
#include <hip/hip_runtime.h>

#define T_LEN 512
#define HD    32
#define FUT   60

// fast sigmoid / tanh: v_exp_f32 + v_rcp_f32 (~1 ulp each; tolerance is 2% absmax)
__device__ __forceinline__ float sigmf_(float v) {
    return __builtin_amdgcn_rcpf(1.0f + __expf(-v));
}
__device__ __forceinline__ float tanhf_(float v) {
    return fmaf(2.0f, __builtin_amdgcn_rcpf(1.0f + __expf(-2.0f * v)), -1.0f);
}

#define LOADROW(dst, mat, row) do {                                         \
    const float4* p_ = (const float4*)((mat) + (size_t)(row) * HD);         \
    _Pragma("unroll")                                                       \
    for (int kk_ = 0; kk_ < HD/4; ++kk_) {                                  \
        float4 a_ = p_[kk_];                                                \
        (dst)[4*kk_+0] = a_.x; (dst)[4*kk_+1] = a_.y;                       \
        (dst)[4*kk_+2] = a_.z; (dst)[4*kk_+3] = a_.w;                       \
    } } while (0)

#define LOADROWSUM(dst, matA, matB, row) do {                               \
    const float4* pa_ = (const float4*)((matA) + (size_t)(row) * HD);       \
    const float4* pb_ = (const float4*)((matB) + (size_t)(row) * HD);       \
    _Pragma("unroll")                                                       \
    for (int kk_ = 0; kk_ < HD/4; ++kk_) {                                  \
        float4 a_ = pa_[kk_], b_ = pb_[kk_];                                \
        (dst)[4*kk_+0] = a_.x + b_.x; (dst)[4*kk_+1] = a_.y + b_.y;         \
        (dst)[4*kk_+2] = a_.z + b_.z; (dst)[4*kk_+3] = a_.w + b_.w;         \
    } } while (0)

// 6 FMAs per k for the encoder (r,z accumulate gx+gh together; n keeps them split)
#define ACC6(k, ee, hh)                                                     \
    s_r = fmaf(wie0[k], (ee), s_r); s_r = fmaf(whe0[k], (hh), s_r);         \
    s_z = fmaf(wie1[k], (ee), s_z); s_z = fmaf(whe1[k], (hh), s_z);         \
    gxn = fmaf(wie2[k], (ee), gxn); ghn = fmaf(whe2[k], (hh), ghn)

// 4 FMAs per k for the decoder (r,z use pre-summed Wih_d+Whh_d)
#define DACC(k, hh)                                                         \
    s_r = fmaf(wr[k], (hh), s_r);  s_z = fmaf(wz[k], (hh), s_z);            \
    gni = fmaf(wni[k], (hh), gni); gnh = fmaf(wnh[k], (hh), gnh)

// block = 64 threads = 1 wave = 2 batch elements (lanes [0:32) -> elem 0, [32:64) -> elem 1)
// grid = 2048/2 = 1024 blocks -> 4 blocks/CU, 1 wave/SIMD. No __syncthreads anywhere:
// each element's cross-lane exchange stays inside one wave; per-wave DS ops are in-order.
__global__ __launch_bounds__(64) void gru_encdec(
    const float* __restrict__ x,
    const float* __restrict__ W_emb, const float* __restrict__ b_emb,
    const float* __restrict__ Wih_e, const float* __restrict__ Whh_e,
    const float* __restrict__ bih_e, const float* __restrict__ bhh_e,
    const float* __restrict__ Wih_d, const float* __restrict__ Whh_d,
    const float* __restrict__ bih_d, const float* __restrict__ bhh_d,
    const float* __restrict__ W_out, const float* __restrict__ b_out,
    float* __restrict__ y)
{
    __shared__ __align__(16) float x_lds[2 * T_LEN * 4];   // 16 KB: full x for both elems
    __shared__ __align__(16) float h_lds[2][HD];
    __shared__ __align__(16) float e_lds[2][2][HD];        // [buf][elem][k] double-buffered

    const int tid = threadIdx.x;
    const int el  = tid >> 5;
    const int j   = tid & 31;

    // ---- stage x (coalesced float4: 1024 float4 / 64 lanes = 16 each) ----
    {
        const float4* xg = (const float4*)(x + (size_t)blockIdx.x * (2 * T_LEN * 4));
        float4* xl = (float4*)x_lds;
        #pragma unroll
        for (int i = 0; i < 16; ++i)
            xl[i * 64 + tid] = xg[i * 64 + tid];
    }

    // ---- encoder weights -> registers (lane j holds rows j, 32+j, 64+j) ----
    float wemb0, wemb1, wemb2, wemb3, bemb;
    {
        float4 v = ((const float4*)W_emb)[j];
        wemb0 = v.x; wemb1 = v.y; wemb2 = v.z; wemb3 = v.w;
        bemb  = b_emb[j];
    }
    float wie0[HD], wie1[HD], wie2[HD];
    float whe0[HD], whe1[HD], whe2[HD];
    LOADROW(wie0, Wih_e, 0*HD + j);
    LOADROW(wie1, Wih_e, 1*HD + j);
    LOADROW(wie2, Wih_e, 2*HD + j);
    LOADROW(whe0, Whh_e, 0*HD + j);
    LOADROW(whe1, Whh_e, 1*HD + j);
    LOADROW(whe2, Whh_e, 2*HD + j);
    const float br  = bih_e[j]      + bhh_e[j];
    const float bz  = bih_e[HD+j]   + bhh_e[HD+j];
    const float bxn = bih_e[2*HD+j];
    const float bhn = bhh_e[2*HD+j];

    // ---- init: h0 = 0; precompute e_0 into buf 0 ----
    h_lds[el][j] = 0.0f;
    float hown = 0.0f;
    {
        const float4 xv = *(const float4*)&x_lds[el * (T_LEN * 4)];
        float ev = fmaf(wemb0, xv.x, fmaf(wemb1, xv.y, fmaf(wemb2, xv.z, fmaf(wemb3, xv.w, bemb))));
        e_lds[0][el][j] = fmaxf(ev, 0.0f);
    }

    // ---- encoder: 512 sequential GRU steps ----
    #pragma unroll 2
    for (int t = 0; t < T_LEN; ++t) {
        const int buf = t & 1;
        float s_r = br, s_z = bz, gxn = bxn, ghn = bhn;
        #pragma unroll
        for (int kk = 0; kk < HD/4; ++kk) {
            const float4 e4 = *(const float4*)&e_lds[buf][el][4*kk];
            const float4 h4 = *(const float4*)&h_lds[el][4*kk];
            ACC6(4*kk+0, e4.x, h4.x);
            ACC6(4*kk+1, e4.y, h4.y);
            ACC6(4*kk+2, e4.z, h4.z);
            ACC6(4*kk+3, e4.w, h4.w);
        }
        // e_{t+1}: independent of the gate chain; fills the transcendental latency
        if (t + 1 < T_LEN) {
            const float4 xv = *(const float4*)&x_lds[(el * T_LEN + t + 1) * 4];
            float ev = fmaf(wemb0, xv.x, fmaf(wemb1, xv.y, fmaf(wemb2, xv.z, fmaf(wemb3, xv.w, bemb))));
            e_lds[buf ^ 1][el][j] = fmaxf(ev, 0.0f);
        }
        const float r = sigmf_(s_r);
        const float z = sigmf_(s_z);
        const float n = tanhf_(fmaf(r, ghn, gxn));
        hown = fmaf(z, hown - n, n);            // (1-z)*n + z*h
        h_lds[el][j] = hown;
    }

    // ---- decoder weights (r,z: Wih_d+Whh_d pre-summed since both see h) ----
    float wr[HD], wz[HD], wni[HD], wnh[HD];
    LOADROWSUM(wr, Wih_d, Whh_d, 0*HD + j);
    LOADROWSUM(wz, Wih_d, Whh_d, 1*HD + j);
    LOADROW(wni, Wih_d, 2*HD + j);
    LOADROW(wnh, Whh_d, 2*HD + j);
    const float dbr  = bih_d[j]      + bhh_d[j];
    const float dbz  = bih_d[HD+j]   + bhh_d[HD+j];
    const float dbni = bih_d[2*HD+j];
    const float dbnh = bhh_d[2*HD+j];
    const float wo0 = W_out[0*HD + j];
    const float wo1 = W_out[1*HD + j];
    const float wo2 = W_out[2*HD + j];
    const float wo3 = W_out[3*HD + j];
    const float bo0 = b_out[0], bo1 = b_out[1], bo2 = b_out[2], bo3 = b_out[3];

    float* yp = y + (size_t)(blockIdx.x * 2 + el) * (FUT * 4);

    // ---- decoder: 60 steps, input == hidden ----
    #pragma unroll 1
    for (int f = 0; f < FUT; ++f) {
        float s_r = dbr, s_z = dbz, gni = dbni, gnh = dbnh;
        #pragma unroll
        for (int kk = 0; kk < HD/4; ++kk) {
            const float4 h4 = *(const float4*)&h_lds[el][4*kk];
            DACC(4*kk+0, h4.x);
            DACC(4*kk+1, h4.y);
            DACC(4*kk+2, h4.z);
            DACC(4*kk+3, h4.w);
        }
        const float r = sigmf_(s_r);
        const float z = sigmf_(s_z);
        const float n = tanhf_(fmaf(r, gnh, gni));
        hown = fmaf(z, hown - n, n);
        h_lds[el][j] = hown;

        // y_f = W_out @ h_f + b_out via butterfly reduce over the 32 lanes
        float p0 = wo0 * hown, p1 = wo1 * hown, p2 = wo2 * hown, p3 = wo3 * hown;
        #pragma unroll
        for (int off = 16; off >= 1; off >>= 1) {
            p0 += __shfl_xor(p0, off, 32);
            p1 += __shfl_xor(p1, off, 32);
            p2 += __shfl_xor(p2, off, 32);
            p3 += __shfl_xor(p3, off, 32);
        }
        if (j == 0) {
            float4 o4 = make_float4(p0 + bo0, p1 + bo1, p2 + bo2, p3 + bo3);
            *(float4*)(yp + f * 4) = o4;
        }
    }
}

extern "C" void kernel_launch(void* const* d_in, const int* in_sizes, int n_in,
                              void* d_out, int out_size, void* d_ws, size_t ws_size,
                              hipStream_t stream) {
    (void)in_sizes; (void)n_in; (void)d_ws; (void)ws_size; (void)out_size;
    gru_encdec<<<dim3(1024), dim3(64), 0, stream>>>(
        (const float*)d_in[0],                            // x
        (const float*)d_in[1],  (const float*)d_in[2],    // W_emb, b_emb
        (const float*)d_in[3],  (const float*)d_in[4],    // Wih_e, Whh_e
        (const float*)d_in[5],  (const float*)d_in[6],    // bih_e, bhh_e
        (const float*)d_in[7],  (const float*)d_in[8],    // Wih_d, Whh_d
        (const float*)d_in[9],  (const float*)d_in[10],   // bih_d, bhh_d
        (const float*)d_in[11], (const float*)d_in[12],   // W_out, b_out
        (float*)d_out);
}

// Round 2
// 282.118 us; speedup vs baseline: 1.1736x; 1.1736x over previous
//
#include <hip/hip_runtime.h>

#define T_LEN 512
#define HD    32
#define FUT   60

typedef float f32x2 __attribute__((ext_vector_type(2)));
typedef float f32x4 __attribute__((ext_vector_type(4)));

// fast sigmoid / tanh via v_exp_f32 + v_rcp_f32 (tolerance is 2% of ref absmax)
__device__ __forceinline__ float sigmf_(float v) {
    return __builtin_amdgcn_rcpf(1.0f + __expf(-v));
}
__device__ __forceinline__ float tanhf_(float v) {
    return fmaf(2.0f, __builtin_amdgcn_rcpf(1.0f + __expf(-2.0f * v)), -1.0f);
}

// packed fp32 FMA (full-rate on CDNA): acc += a * b, 2 lanes of fp32 per instr
#define PKFMA(acc, a, b) \
    asm("v_pk_fma_f32 %0, %1, %2, %0" : "+v"(acc) : "v"(a), "v"(b))

// load 16 floats (this lane's K-half) of row `row` into 8 f32x2 regs
#define LOADH(dst, mat, row) do {                                            \
    const f32x4* p_ = (const f32x4*)((mat) + (size_t)(row) * HD + kbase);    \
    _Pragma("unroll")                                                        \
    for (int q_ = 0; q_ < 4; ++q_) {                                         \
        f32x4 v_ = p_[q_];                                                   \
        (dst)[2*q_]   = (f32x2){v_[0], v_[1]};                               \
        (dst)[2*q_+1] = (f32x2){v_[2], v_[3]};                               \
    } } while (0)

#define LOADHSUM(dst, matA, matB, row) do {                                  \
    const f32x4* pa_ = (const f32x4*)((matA) + (size_t)(row) * HD + kbase);  \
    const f32x4* pb_ = (const f32x4*)((matB) + (size_t)(row) * HD + kbase);  \
    _Pragma("unroll")                                                        \
    for (int q_ = 0; q_ < 4; ++q_) {                                         \
        f32x4 a_ = pa_[q_], b_ = pb_[q_];                                    \
        (dst)[2*q_]   = (f32x2){a_[0] + b_[0], a_[1] + b_[1]};               \
        (dst)[2*q_+1] = (f32x2){a_[2] + b_[2], a_[3] + b_[3]};               \
    } } while (0)

// block = 64 threads = 1 wave = ONE batch element.
// lane l: j = l&31 (gate row within each gate), half = l>>5 (K-half).
// Lane (j,half) accumulates k in [16*half, 16*half+16) of gate rows j, 32+j, 64+j.
// Cross-half combine: one __shfl_xor(·,32) per gate sum. No __syncthreads anywhere
// (single wave per block; per-wave DS ops complete in program order).
__global__ __launch_bounds__(64, 2) void gru_encdec(
    const float* __restrict__ x,
    const float* __restrict__ W_emb, const float* __restrict__ b_emb,
    const float* __restrict__ Wih_e, const float* __restrict__ Whh_e,
    const float* __restrict__ bih_e, const float* __restrict__ bhh_e,
    const float* __restrict__ Wih_d, const float* __restrict__ Whh_d,
    const float* __restrict__ bih_d, const float* __restrict__ bhh_d,
    const float* __restrict__ W_out, const float* __restrict__ b_out,
    float* __restrict__ y)
{
    __shared__ __align__(16) float x_lds[T_LEN * 4];   // 8 KB: this element's full x
    __shared__ __align__(16) float e_lds[2][HD];       // double-buffered embedded input
    __shared__ __align__(16) float h_lds[HD];

    const int l = threadIdx.x;
    const int j = l & 31;
    const int kbase = (l >> 5) * 16;   // this lane's K-half start

    // ---- stage x (512 float4 / 64 lanes = 8 each, coalesced) ----
    {
        const f32x4* xg = (const f32x4*)(x + (size_t)blockIdx.x * (T_LEN * 4));
        f32x4* xl = (f32x4*)x_lds;
        #pragma unroll
        for (int i = 0; i < 8; ++i)
            xl[i * 64 + l] = xg[i * 64 + l];
    }

    // ---- embedder weights (row j) ----
    const f32x4 we = ((const f32x4*)W_emb)[j];
    const float bemb = b_emb[j];

    // ---- encoder weights: 6 half-rows = 96 floats/lane (48 f32x2) ----
    f32x2 wie0[8], wie1[8], wie2[8], whe0[8], whe1[8], whe2[8];
    LOADH(wie0, Wih_e, 0*HD + j);
    LOADH(wie1, Wih_e, 1*HD + j);
    LOADH(wie2, Wih_e, 2*HD + j);
    LOADH(whe0, Whh_e, 0*HD + j);
    LOADH(whe1, Whh_e, 1*HD + j);
    LOADH(whe2, Whh_e, 2*HD + j);
    const float br  = bih_e[j]        + bhh_e[j];
    const float bz  = bih_e[HD + j]   + bhh_e[HD + j];
    const float bxn = bih_e[2*HD + j];
    const float bhn = bhh_e[2*HD + j];

    // ---- init h0 = 0; e_0 into buf 0 ----
    h_lds[j] = 0.0f;
    float hj = 0.0f;
    {
        const f32x4 xv = *(const f32x4*)&x_lds[0];
        float ev = fmaf(we[0], xv[0], fmaf(we[1], xv[1], fmaf(we[2], xv[2], fmaf(we[3], xv[3], bemb))));
        e_lds[0][j] = fmaxf(ev, 0.0f);
    }

    // ---- encoder: 512 sequential GRU steps ----
    #pragma unroll 2
    for (int t = 0; t < T_LEN; ++t) {
        const int buf = t & 1;
        f32x2 e2[8], h2[8];
        #pragma unroll
        for (int q = 0; q < 4; ++q) {   // 2 addrs/wave per read -> conflict-free broadcast
            const f32x4 v = *(const f32x4*)&e_lds[buf][kbase + 4*q];
            e2[2*q] = (f32x2){v[0], v[1]}; e2[2*q+1] = (f32x2){v[2], v[3]};
            const f32x4 w = *(const f32x4*)&h_lds[kbase + 4*q];
            h2[2*q] = (f32x2){w[0], w[1]}; h2[2*q+1] = (f32x2){w[2], w[3]};
        }
        f32x2 ar = {0.f,0.f}, az = {0.f,0.f}, axn = {0.f,0.f}, ahn = {0.f,0.f};
        #pragma unroll
        for (int q = 0; q < 8; ++q) {   // 48 v_pk_fma_f32 = 96 FMAs
            PKFMA(ar,  wie0[q], e2[q]);
            PKFMA(az,  wie1[q], e2[q]);
            PKFMA(axn, wie2[q], e2[q]);
            PKFMA(ar,  whe0[q], h2[q]);
            PKFMA(az,  whe1[q], h2[q]);
            PKFMA(ahn, whe2[q], h2[q]);
        }
        float s_r  = ar[0]  + ar[1];
        float s_z  = az[0]  + az[1];
        float s_xn = axn[0] + axn[1];
        float s_hn = ahn[0] + ahn[1];
        s_r  += __shfl_xor(s_r,  32, 64);
        s_z  += __shfl_xor(s_z,  32, 64);
        s_xn += __shfl_xor(s_xn, 32, 64);
        s_hn += __shfl_xor(s_hn, 32, 64);
        // prefetch e_{t+1} (independent of gate chain; fills trans latency)
        if (t + 1 < T_LEN) {
            const f32x4 xv = *(const f32x4*)&x_lds[(t + 1) * 4];
            float ev = fmaf(we[0], xv[0], fmaf(we[1], xv[1], fmaf(we[2], xv[2], fmaf(we[3], xv[3], bemb))));
            e_lds[buf ^ 1][j] = fmaxf(ev, 0.0f);
        }
        const float r = sigmf_(s_r + br);
        const float z = sigmf_(s_z + bz);
        const float n = tanhf_(fmaf(r, s_hn + bhn, s_xn + bxn));
        hj = fmaf(z, hj - n, n);        // (1-z)*n + z*h
        h_lds[j] = hj;
    }

    // ---- decoder weights: 4 half-rows = 64 floats/lane (r,z pre-summed) ----
    f32x2 wdr[8], wdz[8], wni[8], wnh[8];
    LOADHSUM(wdr, Wih_d, Whh_d, 0*HD + j);
    LOADHSUM(wdz, Wih_d, Whh_d, 1*HD + j);
    LOADH(wni, Wih_d, 2*HD + j);
    LOADH(wnh, Whh_d, 2*HD + j);
    const float dbr  = bih_d[j]        + bhh_d[j];
    const float dbz  = bih_d[HD + j]   + bhh_d[HD + j];
    const float dbni = bih_d[2*HD + j];
    const float dbnh = bhh_d[2*HD + j];
    const float wo0 = W_out[0*HD + j];
    const float wo1 = W_out[1*HD + j];
    const float wo2 = W_out[2*HD + j];
    const float wo3 = W_out[3*HD + j];
    const float bo0 = b_out[0], bo1 = b_out[1], bo2 = b_out[2], bo3 = b_out[3];

    float* yp = y + (size_t)blockIdx.x * (FUT * 4);

    // ---- decoder: 60 steps, input == hidden ----
    #pragma unroll 1
    for (int f = 0; f < FUT; ++f) {
        f32x2 h2[8];
        #pragma unroll
        for (int q = 0; q < 4; ++q) {
            const f32x4 w = *(const f32x4*)&h_lds[kbase + 4*q];
            h2[2*q] = (f32x2){w[0], w[1]}; h2[2*q+1] = (f32x2){w[2], w[3]};
        }
        f32x2 arr = {0.f,0.f}, azz = {0.f,0.f}, ani = {0.f,0.f}, anh = {0.f,0.f};
        #pragma unroll
        for (int q = 0; q < 8; ++q) {   // 32 v_pk_fma_f32 = 64 FMAs
            PKFMA(arr, wdr[q], h2[q]);
            PKFMA(azz, wdz[q], h2[q]);
            PKFMA(ani, wni[q], h2[q]);
            PKFMA(anh, wnh[q], h2[q]);
        }
        float s_r  = arr[0] + arr[1];
        float s_z  = azz[0] + azz[1];
        float s_ni = ani[0] + ani[1];
        float s_nh = anh[0] + anh[1];
        s_r  += __shfl_xor(s_r,  32, 64);
        s_z  += __shfl_xor(s_z,  32, 64);
        s_ni += __shfl_xor(s_ni, 32, 64);
        s_nh += __shfl_xor(s_nh, 32, 64);
        const float r = sigmf_(s_r + dbr);
        const float z = sigmf_(s_z + dbz);
        const float n = tanhf_(fmaf(r, s_nh + dbnh, s_ni + dbni));
        hj = fmaf(z, hj - n, n);
        h_lds[j] = hj;

        // y_f = W_out @ h_f + b_out: butterfly within each 32-half (both halves
        // hold the complete h vector across lanes), lane 0 writes.
        float p0 = wo0 * hj, p1 = wo1 * hj, p2 = wo2 * hj, p3 = wo3 * hj;
        #pragma unroll
        for (int off = 16; off >= 1; off >>= 1) {
            p0 += __shfl_xor(p0, off, 64);
            p1 += __shfl_xor(p1, off, 64);
            p2 += __shfl_xor(p2, off, 64);
            p3 += __shfl_xor(p3, off, 64);
        }
        if (l == 0) {
            *(f32x4*)(yp + f * 4) = (f32x4){p0 + bo0, p1 + bo1, p2 + bo2, p3 + bo3};
        }
    }
}

extern "C" void kernel_launch(void* const* d_in, const int* in_sizes, int n_in,
                              void* d_out, int out_size, void* d_ws, size_t ws_size,
                              hipStream_t stream) {
    (void)in_sizes; (void)n_in; (void)d_ws; (void)ws_size; (void)out_size;
    gru_encdec<<<dim3(2048), dim3(64), 0, stream>>>(
        (const float*)d_in[0],                            // x
        (const float*)d_in[1],  (const float*)d_in[2],    // W_emb, b_emb
        (const float*)d_in[3],  (const float*)d_in[4],    // Wih_e, Whh_e
        (const float*)d_in[5],  (const float*)d_in[6],    // bih_e, bhh_e
        (const float*)d_in[7],  (const float*)d_in[8],    // Wih_d, Whh_d
        (const float*)d_in[9],  (const float*)d_in[10],   // bih_d, bhh_d
        (const float*)d_in[11], (const float*)d_in[12],   // W_out, b_out
        (float*)d_out);
}

// Round 4
// 254.977 us; speedup vs baseline: 1.2986x; 1.1064x over previous
//
#include <hip/hip_runtime.h>

#define T_LEN 512
#define HD    32
#define FUT   60

typedef float    f32x4 __attribute__((ext_vector_type(4)));
typedef _Float16 f16x2 __attribute__((ext_vector_type(2)));
typedef _Float16 f16x8 __attribute__((ext_vector_type(8)));

union H8 { f16x8 v; f16x2 p[4]; };

// v_dot2_f32_f16: d = a.x*b.x + a.y*b.y + c  (f16 mul, f32 accumulate, full-rate)
__device__ __forceinline__ float dot2(f16x2 a, f16x2 b, float c) {
#if __has_builtin(__builtin_amdgcn_fdot2)
    return __builtin_amdgcn_fdot2(a, b, c, false);
#else
    float acc = c;
    asm("v_dot2_f32_f16 %0, %1, %2, %0" : "+v"(acc) : "v"(a), "v"(b));
    return acc;
#endif
}

// fast sigmoid / tanh via v_exp_f32 + v_rcp_f32 (tolerance is 2% of ref absmax)
__device__ __forceinline__ float sigmf_(float v) {
    return __builtin_amdgcn_rcpf(1.0f + __expf(-v));
}
__device__ __forceinline__ float tanhf_(float v) {
    return fmaf(2.0f, __builtin_amdgcn_rcpf(1.0f + __expf(-2.0f * v)), -1.0f);
}

// load 16 f32 (this lane's K-half of row `row`), convert RTN to 8 f16 pairs
#define LOADH16(dst, mat, row) do {                                          \
    const f32x4* p_ = (const f32x4*)((mat) + (size_t)(row) * HD + kbase);    \
    _Pragma("unroll")                                                        \
    for (int q_ = 0; q_ < 4; ++q_) {                                         \
        f32x4 v_ = p_[q_];                                                   \
        (dst)[2*q_]   = (f16x2){(_Float16)v_[0], (_Float16)v_[1]};           \
        (dst)[2*q_+1] = (f16x2){(_Float16)v_[2], (_Float16)v_[3]};           \
    } } while (0)

#define LOADH16SUM(dst, matA, matB, row) do {                                \
    const f32x4* pa_ = (const f32x4*)((matA) + (size_t)(row) * HD + kbase);  \
    const f32x4* pb_ = (const f32x4*)((matB) + (size_t)(row) * HD + kbase);  \
    _Pragma("unroll")                                                        \
    for (int q_ = 0; q_ < 4; ++q_) {                                         \
        f32x4 a_ = pa_[q_], b_ = pb_[q_];                                    \
        (dst)[2*q_]   = (f16x2){(_Float16)(a_[0]+b_[0]), (_Float16)(a_[1]+b_[1])}; \
        (dst)[2*q_+1] = (f16x2){(_Float16)(a_[2]+b_[2]), (_Float16)(a_[3]+b_[3])}; \
    } } while (0)

// block = 64 threads = 1 wave = ONE batch element.
// lane l: j = l&31 (hidden unit / gate row), half = l>>5 (K-half).
// Lane (j,half) owns k in [16*half, 16*half+16) of gate rows j, 32+j, 64+j,
// stored as f16 pairs (48 VGPRs enc, 32 dec). f32 accumulate via v_dot2_f32_f16.
// Cross-half combine: one __shfl_xor(.,32) per gate. No __syncthreads anywhere.
__global__ __launch_bounds__(64, 2) void gru_encdec(
    const float* __restrict__ x,
    const float* __restrict__ W_emb, const float* __restrict__ b_emb,
    const float* __restrict__ Wih_e, const float* __restrict__ Whh_e,
    const float* __restrict__ bih_e, const float* __restrict__ bhh_e,
    const float* __restrict__ Wih_d, const float* __restrict__ Whh_d,
    const float* __restrict__ bih_d, const float* __restrict__ bhh_d,
    const float* __restrict__ W_out, const float* __restrict__ b_out,
    float* __restrict__ y)
{
    __shared__ __align__(16) float    x_lds[T_LEN * 4];   // 8 KB f32
    __shared__ __align__(16) _Float16 e_lds[2][HD];       // f16, double-buffered
    __shared__ __align__(16) _Float16 h_lds[HD];          // f16 copy of h for matvec

    const int l = threadIdx.x;
    const int j = l & 31;
    const int half = l >> 5;
    const int kbase = half * 16;

    // ---- stage x (512 float4 / 64 lanes = 8 each, coalesced) ----
    {
        const f32x4* xg = (const f32x4*)(x + (size_t)blockIdx.x * (T_LEN * 4));
        f32x4* xl = (f32x4*)x_lds;
        #pragma unroll
        for (int i = 0; i < 8; ++i)
            xl[i * 64 + l] = xg[i * 64 + l];
    }

    // ---- embedder weights (row j), f32 ----
    const f32x4 we = ((const f32x4*)W_emb)[j];
    const float bemb = b_emb[j];

    // ---- encoder weights: 6 half-rows = 96 f16 = 48 VGPRs ----
    f16x2 wie0[8], wie1[8], wie2[8], whe0[8], whe1[8], whe2[8];
    LOADH16(wie0, Wih_e, 0*HD + j);
    LOADH16(wie1, Wih_e, 1*HD + j);
    LOADH16(wie2, Wih_e, 2*HD + j);
    LOADH16(whe0, Whh_e, 0*HD + j);
    LOADH16(whe1, Whh_e, 1*HD + j);
    LOADH16(whe2, Whh_e, 2*HD + j);
    // biases folded into half-0 accumulator init
    const float br_i  = half ? 0.0f : bih_e[j] + bhh_e[j];
    const float bz_i  = half ? 0.0f : bih_e[HD + j] + bhh_e[HD + j];
    const float bxn_i = half ? 0.0f : bih_e[2*HD + j];
    const float bhn_i = half ? 0.0f : bhh_e[2*HD + j];

    // ---- init h0 = 0; e_0 into buf 0 ----
    h_lds[j] = (_Float16)0.0f;   // both halves write identical bits: benign
    float hj = 0.0f;
    {
        const f32x4 xv = *(const f32x4*)&x_lds[0];
        float ev = fmaf(we[0], xv[0], fmaf(we[1], xv[1], fmaf(we[2], xv[2], fmaf(we[3], xv[3], bemb))));
        e_lds[0][j] = (_Float16)fmaxf(ev, 0.0f);
    }

    // ---- encoder: 512 sequential GRU steps ----
    #pragma unroll 2
    for (int t = 0; t < T_LEN; ++t) {
        const int buf = t & 1;
        // 4x ds_read_b128: this half's 16 f16 of e and h (2 addrs/wave -> broadcast)
        const f16x8* ep = (const f16x8*)&e_lds[buf][kbase];
        const f16x8* hp = (const f16x8*)&h_lds[kbase];
        H8 ue0, ue1, uh0, uh1;
        ue0.v = ep[0]; ue1.v = ep[1];
        uh0.v = hp[0]; uh1.v = hp[1];
        // 48 v_dot2_f32_f16 = 96 MACs, 6 independent chains of 8
        float a_re = br_i, a_ze = bz_i, a_xn = bxn_i;
        float a_rh = 0.0f, a_zh = 0.0f, a_hn = bhn_i;
        #pragma unroll
        for (int q = 0; q < 4; ++q) {
            a_re = dot2(wie0[q], ue0.p[q], a_re);
            a_ze = dot2(wie1[q], ue0.p[q], a_ze);
            a_xn = dot2(wie2[q], ue0.p[q], a_xn);
            a_rh = dot2(whe0[q], uh0.p[q], a_rh);
            a_zh = dot2(whe1[q], uh0.p[q], a_zh);
            a_hn = dot2(whe2[q], uh0.p[q], a_hn);
        }
        #pragma unroll
        for (int q = 0; q < 4; ++q) {
            a_re = dot2(wie0[q + 4], ue1.p[q], a_re);
            a_ze = dot2(wie1[q + 4], ue1.p[q], a_ze);
            a_xn = dot2(wie2[q + 4], ue1.p[q], a_xn);
            a_rh = dot2(whe0[q + 4], uh1.p[q], a_rh);
            a_zh = dot2(whe1[q + 4], uh1.p[q], a_zh);
            a_hn = dot2(whe2[q + 4], uh1.p[q], a_hn);
        }
        float s_r  = a_re + a_rh;
        float s_z  = a_ze + a_zh;
        float s_xn = a_xn;
        float s_hn = a_hn;
        s_r  += __shfl_xor(s_r,  32, 64);
        s_z  += __shfl_xor(s_z,  32, 64);
        s_xn += __shfl_xor(s_xn, 32, 64);
        s_hn += __shfl_xor(s_hn, 32, 64);
        // prefetch e_{t+1} (independent; fills transcendental latency)
        if (t + 1 < T_LEN) {
            const f32x4 xv = *(const f32x4*)&x_lds[(t + 1) * 4];
            float ev = fmaf(we[0], xv[0], fmaf(we[1], xv[1], fmaf(we[2], xv[2], fmaf(we[3], xv[3], bemb))));
            e_lds[buf ^ 1][j] = (_Float16)fmaxf(ev, 0.0f);
        }
        const float r = sigmf_(s_r);
        const float z = sigmf_(s_z);
        const float n = tanhf_(fmaf(r, s_hn, s_xn));
        hj = fmaf(z, hj - n, n);        // (1-z)*n + z*h, state stays f32
        h_lds[j] = (_Float16)hj;
    }

    // ---- decoder weights: 4 half-rows = 64 f16 = 32 VGPRs (r,z pre-summed) ----
    f16x2 wdr[8], wdz[8], wni[8], wnh[8];
    LOADH16SUM(wdr, Wih_d, Whh_d, 0*HD + j);
    LOADH16SUM(wdz, Wih_d, Whh_d, 1*HD + j);
    LOADH16(wni, Wih_d, 2*HD + j);
    LOADH16(wnh, Whh_d, 2*HD + j);
    const float dbr_i  = half ? 0.0f : bih_d[j] + bhh_d[j];
    const float dbz_i  = half ? 0.0f : bih_d[HD + j] + bhh_d[HD + j];
    const float dbni_i = half ? 0.0f : bih_d[2*HD + j];
    const float dbnh_i = half ? 0.0f : bhh_d[2*HD + j];
    const float wo0 = W_out[0*HD + j];
    const float wo1 = W_out[1*HD + j];
    const float wo2 = W_out[2*HD + j];
    const float wo3 = W_out[3*HD + j];
    const float bo0 = b_out[0], bo1 = b_out[1], bo2 = b_out[2], bo3 = b_out[3];

    float* yp = y + (size_t)blockIdx.x * (FUT * 4);

    // ---- decoder: 60 steps, input == hidden ----
    #pragma unroll 1
    for (int f = 0; f < FUT; ++f) {
        const f16x8* hp = (const f16x8*)&h_lds[kbase];
        H8 uh0, uh1;
        uh0.v = hp[0]; uh1.v = hp[1];
        float a_r = dbr_i, a_z = dbz_i, a_ni = dbni_i, a_nh = dbnh_i;
        #pragma unroll
        for (int q = 0; q < 4; ++q) {   // 32 dot2 = 64 MACs
            a_r  = dot2(wdr[q], uh0.p[q], a_r);
            a_z  = dot2(wdz[q], uh0.p[q], a_z);
            a_ni = dot2(wni[q], uh0.p[q], a_ni);
            a_nh = dot2(wnh[q], uh0.p[q], a_nh);
        }
        #pragma unroll
        for (int q = 0; q < 4; ++q) {
            a_r  = dot2(wdr[q + 4], uh1.p[q], a_r);
            a_z  = dot2(wdz[q + 4], uh1.p[q], a_z);
            a_ni = dot2(wni[q + 4], uh1.p[q], a_ni);
            a_nh = dot2(wnh[q + 4], uh1.p[q], a_nh);
        }
        float s_r = a_r, s_z = a_z, s_ni = a_ni, s_nh = a_nh;
        s_r  += __shfl_xor(s_r,  32, 64);
        s_z  += __shfl_xor(s_z,  32, 64);
        s_ni += __shfl_xor(s_ni, 32, 64);
        s_nh += __shfl_xor(s_nh, 32, 64);
        const float r = sigmf_(s_r);
        const float z = sigmf_(s_z);
        const float n = tanhf_(fmaf(r, s_nh, s_ni));
        hj = fmaf(z, hj - n, n);
        h_lds[j] = (_Float16)hj;

        // y_f = W_out @ h_f + b_out: butterfly across all 64 lanes, lane 0 writes
        float p0 = wo0 * hj, p1 = wo1 * hj, p2 = wo2 * hj, p3 = wo3 * hj;
        #pragma unroll
        for (int off = 16; off >= 1; off >>= 1) {
            p0 += __shfl_xor(p0, off, 64);
            p1 += __shfl_xor(p1, off, 64);
            p2 += __shfl_xor(p2, off, 64);
            p3 += __shfl_xor(p3, off, 64);
        }
        if (l == 0) {
            *(f32x4*)(yp + f * 4) = (f32x4){p0 + bo0, p1 + bo1, p2 + bo2, p3 + bo3};
        }
    }
}

extern "C" void kernel_launch(void* const* d_in, const int* in_sizes, int n_in,
                              void* d_out, int out_size, void* d_ws, size_t ws_size,
                              hipStream_t stream) {
    (void)in_sizes; (void)n_in; (void)d_ws; (void)ws_size; (void)out_size;
    gru_encdec<<<dim3(2048), dim3(64), 0, stream>>>(
        (const float*)d_in[0],                            // x
        (const float*)d_in[1],  (const float*)d_in[2],    // W_emb, b_emb
        (const float*)d_in[3],  (const float*)d_in[4],    // Wih_e, Whh_e
        (const float*)d_in[5],  (const float*)d_in[6],    // bih_e, bhh_e
        (const float*)d_in[7],  (const float*)d_in[8],    // Wih_d, Whh_d
        (const float*)d_in[9],  (const float*)d_in[10],   // bih_d, bhh_d
        (const float*)d_in[11], (const float*)d_in[12],   // W_out, b_out
        (float*)d_out);
}

// Round 5
// 239.832 us; speedup vs baseline: 1.3806x; 1.0631x over previous
//
#include <hip/hip_runtime.h>

#define T_LEN 512
#define HD    32
#define FUT   60

typedef float    f32x4 __attribute__((ext_vector_type(4)));
typedef _Float16 f16x2 __attribute__((ext_vector_type(2)));
typedef _Float16 f16x8 __attribute__((ext_vector_type(8)));
typedef unsigned int u32x2 __attribute__((ext_vector_type(2)));

union H8 { f16x8 v; f16x2 p[4]; };

// v_dot2_f32_f16: d = a.x*b.x + a.y*b.y + c  (f16 mul, f32 accumulate, full-rate)
__device__ __forceinline__ float dot2(f16x2 a, f16x2 b, float c) {
#if __has_builtin(__builtin_amdgcn_fdot2)
    return __builtin_amdgcn_fdot2(a, b, c, false);
#else
    float acc = c;
    asm("v_dot2_f32_f16 %0, %1, %2, %0" : "+v"(acc) : "v"(a), "v"(b));
    return acc;
#endif
}

// v_permlane32_swap_b32: a' = [a_lo | b_lo], b' = [a_hi | b_hi]  (pure VALU, no DS)
__device__ __forceinline__ void swap_halves(float& a, float& b) {
#if __has_builtin(__builtin_amdgcn_permlane32_swap)
    u32x2 r = __builtin_amdgcn_permlane32_swap(
        __float_as_uint(a), __float_as_uint(b), false, false);
    a = __uint_as_float(r.x);
    b = __uint_as_float(r.y);
#else
    const bool hi = (threadIdx.x & 32) != 0;
    float as = __shfl_xor(a, 32, 64);
    float bs = __shfl_xor(b, 32, 64);
    float na = hi ? bs : a;
    float nb = hi ? b  : as;
    a = na; b = nb;
#endif
}

// fast sigmoid / tanh via v_exp_f32 + v_rcp_f32 (tolerance is 2% of ref absmax)
__device__ __forceinline__ float sigmf_(float v) {
    return __builtin_amdgcn_rcpf(1.0f + __expf(-v));
}
__device__ __forceinline__ float tanhf_(float v) {
    return fmaf(2.0f, __builtin_amdgcn_rcpf(1.0f + __expf(-2.0f * v)), -1.0f);
}

// load 16 f32 (this lane's K-half of row `row`), convert RTN to 8 f16 pairs
#define LOADH16(dst, mat, row) do {                                          \
    const f32x4* p_ = (const f32x4*)((mat) + (size_t)(row) * HD + kbase);    \
    _Pragma("unroll")                                                        \
    for (int q_ = 0; q_ < 4; ++q_) {                                         \
        f32x4 v_ = p_[q_];                                                   \
        (dst)[2*q_]   = (f16x2){(_Float16)v_[0], (_Float16)v_[1]};           \
        (dst)[2*q_+1] = (f16x2){(_Float16)v_[2], (_Float16)v_[3]};           \
    } } while (0)

#define LOADH16SUM(dst, matA, matB, row) do {                                \
    const f32x4* pa_ = (const f32x4*)((matA) + (size_t)(row) * HD + kbase);  \
    const f32x4* pb_ = (const f32x4*)((matB) + (size_t)(row) * HD + kbase);  \
    _Pragma("unroll")                                                        \
    for (int q_ = 0; q_ < 4; ++q_) {                                         \
        f32x4 a_ = pa_[q_], b_ = pb_[q_];                                    \
        (dst)[2*q_]   = (f16x2){(_Float16)(a_[0]+b_[0]), (_Float16)(a_[1]+b_[1])}; \
        (dst)[2*q_+1] = (f16x2){(_Float16)(a_[2]+b_[2]), (_Float16)(a_[3]+b_[3])}; \
    } } while (0)

// block = 64 threads = 1 wave = ONE batch element.
// lane l: j = l&31 (hidden unit / gate row), half = l>>5 (K-half).
// Lane (j,half) owns k in [16*half, 16*half+16) of gate rows j, 32+j, 64+j.
// Gate-sum merge + rebroadcast via v_permlane32_swap (no DS on the serial path).
// amdgpu_waves_per_eu(2,2): target EXACTLY 2 waves/SIMD -> 256-VGPR budget, no
// allocator squeeze to 64 regs (R4's spill-to-AGPR pathology: 221 VALU/step).
__global__ __launch_bounds__(64) __attribute__((amdgpu_waves_per_eu(2, 2)))
void gru_encdec(
    const float* __restrict__ x,
    const float* __restrict__ W_emb, const float* __restrict__ b_emb,
    const float* __restrict__ Wih_e, const float* __restrict__ Whh_e,
    const float* __restrict__ bih_e, const float* __restrict__ bhh_e,
    const float* __restrict__ Wih_d, const float* __restrict__ Whh_d,
    const float* __restrict__ bih_d, const float* __restrict__ bhh_d,
    const float* __restrict__ W_out, const float* __restrict__ b_out,
    float* __restrict__ y)
{
    __shared__ __align__(16) float    x_lds[T_LEN * 4];   // 8 KB f32
    __shared__ __align__(16) _Float16 e_lds[2][HD];       // f16, double-buffered
    __shared__ __align__(16) _Float16 h_lds[HD];          // f16 copy of h for matvec

    const int l = threadIdx.x;
    const int j = l & 31;
    const int half = l >> 5;
    const int kbase = half * 16;

    // ---- stage x (512 float4 / 64 lanes = 8 each, coalesced) ----
    {
        const f32x4* xg = (const f32x4*)(x + (size_t)blockIdx.x * (T_LEN * 4));
        f32x4* xl = (f32x4*)x_lds;
        #pragma unroll
        for (int i = 0; i < 8; ++i)
            xl[i * 64 + l] = xg[i * 64 + l];
    }

    // ---- embedder weights (row j), f32 ----
    const f32x4 we = ((const f32x4*)W_emb)[j];
    const float bemb = b_emb[j];

    // ---- encoder weights: 6 half-rows = 96 f16 = 48 VGPRs ----
    f16x2 wie0[8], wie1[8], wie2[8], whe0[8], whe1[8], whe2[8];
    LOADH16(wie0, Wih_e, 0*HD + j);
    LOADH16(wie1, Wih_e, 1*HD + j);
    LOADH16(wie2, Wih_e, 2*HD + j);
    LOADH16(whe0, Whh_e, 0*HD + j);
    LOADH16(whe1, Whh_e, 1*HD + j);
    LOADH16(whe2, Whh_e, 2*HD + j);
    // biases folded into half-0 accumulator init
    const float br_i  = half ? 0.0f : bih_e[j] + bhh_e[j];
    const float bz_i  = half ? 0.0f : bih_e[HD + j] + bhh_e[HD + j];
    const float bxn_i = half ? 0.0f : bih_e[2*HD + j];
    const float bhn_i = half ? 0.0f : bhh_e[2*HD + j];

    // ---- init h0 = 0; e_0 into buf 0 ----
    h_lds[j] = (_Float16)0.0f;   // both halves write identical bits: benign
    float hj = 0.0f;
    {
        const f32x4 xv = *(const f32x4*)&x_lds[0];
        float ev = fmaf(we[0], xv[0], fmaf(we[1], xv[1], fmaf(we[2], xv[2], fmaf(we[3], xv[3], bemb))));
        e_lds[0][j] = (_Float16)fmaxf(ev, 0.0f);
    }

    // ---- encoder: 512 sequential GRU steps ----
    #pragma unroll 2
    for (int t = 0; t < T_LEN; ++t) {
        const int buf = t & 1;
        // 4x ds_read_b128: this half's 16 f16 of e and h (2 addrs/wave -> broadcast)
        const f16x8* ep = (const f16x8*)&e_lds[buf][kbase];
        const f16x8* hp = (const f16x8*)&h_lds[kbase];
        H8 ue0, ue1, uh0, uh1;
        ue0.v = ep[0]; ue1.v = ep[1];
        uh0.v = hp[0]; uh1.v = hp[1];
        // 48 v_dot2_f32_f16 = 96 MACs, 6 independent chains of 8
        float a_re = br_i, a_ze = bz_i, a_xn = bxn_i;
        float a_rh = 0.0f, a_zh = 0.0f, a_hn = bhn_i;
        #pragma unroll
        for (int q = 0; q < 4; ++q) {
            a_re = dot2(wie0[q], ue0.p[q], a_re);
            a_ze = dot2(wie1[q], ue0.p[q], a_ze);
            a_xn = dot2(wie2[q], ue0.p[q], a_xn);
            a_rh = dot2(whe0[q], uh0.p[q], a_rh);
            a_zh = dot2(whe1[q], uh0.p[q], a_zh);
            a_hn = dot2(whe2[q], uh0.p[q], a_hn);
        }
        #pragma unroll
        for (int q = 0; q < 4; ++q) {
            a_re = dot2(wie0[q + 4], ue1.p[q], a_re);
            a_ze = dot2(wie1[q + 4], ue1.p[q], a_ze);
            a_xn = dot2(wie2[q + 4], ue1.p[q], a_xn);
            a_rh = dot2(whe0[q + 4], uh1.p[q], a_rh);
            a_zh = dot2(whe1[q + 4], uh1.p[q], a_zh);
            a_hn = dot2(whe2[q + 4], uh1.p[q], a_hn);
        }
        // merge K-halves + rebroadcast via permlane32_swap (all-VALU):
        float pr  = a_re + a_rh;     // this lane's r partial
        float pz  = a_ze + a_zh;     // this lane's z partial
        float pxn = a_xn, phn = a_hn;
        swap_halves(pr, pz);         // pr=[r_p0|z_p0], pz=[r_p1|z_p1]
        float uz = pr + pz;          // [r_full(j) | z_full(j)]
        swap_halves(pxn, phn);
        float uv = pxn + phn;        // [xn_full(j) | hn_full(j)]
        // prefetch e_{t+1} (independent; fills transcendental latency)
        if (t + 1 < T_LEN) {
            const f32x4 xv = *(const f32x4*)&x_lds[(t + 1) * 4];
            float ev = fmaf(we[0], xv[0], fmaf(we[1], xv[1], fmaf(we[2], xv[2], fmaf(we[3], xv[3], bemb))));
            e_lds[buf ^ 1][j] = (_Float16)fmaxf(ev, 0.0f);
        }
        float g = sigmf_(uz);        // ONE sigmoid serves r (lo half) and z (hi half)
        float g2 = g, v2 = uv;
        swap_halves(g, g2);          // g = r everywhere, g2 = z everywhere
        swap_halves(uv, v2);         // uv = xn everywhere, v2 = hn everywhere
        const float n = tanhf_(fmaf(g, v2, uv));
        hj = fmaf(g2, hj - n, n);    // (1-z)*n + z*h, state stays f32
        h_lds[j] = (_Float16)hj;
    }

    // ---- decoder weights: 4 half-rows = 64 f16 = 32 VGPRs (r,z pre-summed) ----
    f16x2 wdr[8], wdz[8], wni[8], wnh[8];
    LOADH16SUM(wdr, Wih_d, Whh_d, 0*HD + j);
    LOADH16SUM(wdz, Wih_d, Whh_d, 1*HD + j);
    LOADH16(wni, Wih_d, 2*HD + j);
    LOADH16(wnh, Whh_d, 2*HD + j);
    const float dbr_i  = half ? 0.0f : bih_d[j] + bhh_d[j];
    const float dbz_i  = half ? 0.0f : bih_d[HD + j] + bhh_d[HD + j];
    const float dbni_i = half ? 0.0f : bih_d[2*HD + j];
    const float dbnh_i = half ? 0.0f : bhh_d[2*HD + j];
    const float wo0 = W_out[0*HD + j];
    const float wo1 = W_out[1*HD + j];
    const float wo2 = W_out[2*HD + j];
    const float wo3 = W_out[3*HD + j];
    const float bo0 = b_out[0], bo1 = b_out[1], bo2 = b_out[2], bo3 = b_out[3];

    float* yp = y + (size_t)blockIdx.x * (FUT * 4);

    // ---- decoder: 60 steps, input == hidden ----
    #pragma unroll 1
    for (int f = 0; f < FUT; ++f) {
        const f16x8* hp = (const f16x8*)&h_lds[kbase];
        H8 uh0, uh1;
        uh0.v = hp[0]; uh1.v = hp[1];
        float a_r = dbr_i, a_z = dbz_i, a_ni = dbni_i, a_nh = dbnh_i;
        #pragma unroll
        for (int q = 0; q < 4; ++q) {   // 32 dot2 = 64 MACs
            a_r  = dot2(wdr[q], uh0.p[q], a_r);
            a_z  = dot2(wdz[q], uh0.p[q], a_z);
            a_ni = dot2(wni[q], uh0.p[q], a_ni);
            a_nh = dot2(wnh[q], uh0.p[q], a_nh);
        }
        #pragma unroll
        for (int q = 0; q < 4; ++q) {
            a_r  = dot2(wdr[q + 4], uh1.p[q], a_r);
            a_z  = dot2(wdz[q + 4], uh1.p[q], a_z);
            a_ni = dot2(wni[q + 4], uh1.p[q], a_ni);
            a_nh = dot2(wnh[q + 4], uh1.p[q], a_nh);
        }
        float pr = a_r, pz = a_z, pni = a_ni, pnh = a_nh;
        swap_halves(pr, pz);
        float uz = pr + pz;          // [r_full | z_full]
        swap_halves(pni, pnh);
        float uv = pni + pnh;        // [ni_full | nh_full]
        float g = sigmf_(uz);
        float g2 = g, v2 = uv;
        swap_halves(g, g2);          // g = r, g2 = z (all lanes)
        swap_halves(uv, v2);         // uv = ni, v2 = nh (all lanes)
        const float n = tanhf_(fmaf(g, v2, uv));
        hj = fmaf(g2, hj - n, n);
        h_lds[j] = (_Float16)hj;

        // y_f = W_out @ h_f + b_out: butterfly (both halves identical), lane 0 writes
        float p0 = wo0 * hj, p1 = wo1 * hj, p2 = wo2 * hj, p3 = wo3 * hj;
        #pragma unroll
        for (int off = 16; off >= 1; off >>= 1) {
            p0 += __shfl_xor(p0, off, 64);
            p1 += __shfl_xor(p1, off, 64);
            p2 += __shfl_xor(p2, off, 64);
            p3 += __shfl_xor(p3, off, 64);
        }
        if (l == 0) {
            *(f32x4*)(yp + f * 4) = (f32x4){p0 + bo0, p1 + bo1, p2 + bo2, p3 + bo3};
        }
    }
}

extern "C" void kernel_launch(void* const* d_in, const int* in_sizes, int n_in,
                              void* d_out, int out_size, void* d_ws, size_t ws_size,
                              hipStream_t stream) {
    (void)in_sizes; (void)n_in; (void)d_ws; (void)ws_size; (void)out_size;
    gru_encdec<<<dim3(2048), dim3(64), 0, stream>>>(
        (const float*)d_in[0],                            // x
        (const float*)d_in[1],  (const float*)d_in[2],    // W_emb, b_emb
        (const float*)d_in[3],  (const float*)d_in[4],    // Wih_e, Whh_e
        (const float*)d_in[5],  (const float*)d_in[6],    // bih_e, bhh_e
        (const float*)d_in[7],  (const float*)d_in[8],    // Wih_d, Whh_d
        (const float*)d_in[9],  (const float*)d_in[10],   // bih_d, bhh_d
        (const float*)d_in[11], (const float*)d_in[12],   // W_out, b_out
        (float*)d_out);
}